// Round 1
// baseline (377.656 us; speedup 1.0000x reference)
//
#include <hip/hip_runtime.h>

// Problem: B=32, C=3, H=W=512, fp32.
// Pipeline: x^gamma -> *wb -> contrast about per-plane mean (clip 0..1)
//           -> depthwise 3x3 sharpen (center 9, ring -1) -> blend by s -> clip.
// Plan: kernel 1 computes per-plane sums of (x^g * wb) (96 floats in d_ws),
//       kernel 2 fuses everything else with an LDS tile (+1 halo).

#define HH 512
#define WW 512
#define NPLANE (HH * WW)
#define NPLANES 96            // B*C = 32*3
#define CHUNKS 8              // blocks per plane in the mean kernel

__device__ __forceinline__ float tfm(float v, float g, float wbc, float mean, float ct) {
    float p = __powf(v, g) * wbc;              // x^gamma * wb
    float t = (p - mean) * ct + mean;          // contrast about mean
    return __saturatef(t);                     // clip to [0,1]
}

// ---------------- Kernel 1: per-plane sums of x^g * wb ----------------
// grid = NPLANES*CHUNKS blocks, 256 threads. Each chunk covers 32768 elems
// = 8192 float4 = 256 threads x 32 iters. Block partials -> atomicAdd.
__global__ __launch_bounds__(256) void mean_kernel(
    const float* __restrict__ x,
    const float* __restrict__ gamma,
    const float* __restrict__ wb,
    float* __restrict__ sums)
{
    const int blk   = blockIdx.x;
    const int plane = blk / CHUNKS;
    const int chunk = blk % CHUNKS;
    const int b     = plane / 3;
    const float g   = gamma[b];
    const float wbc = wb[plane];               // wb flat [B,3] == plane index

    const float4* xp = (const float4*)(x + (size_t)plane * NPLANE)
                       + (size_t)chunk * (NPLANE / CHUNKS / 4);
    const int tid = threadIdx.x;

    float acc = 0.f;
    #pragma unroll
    for (int i = 0; i < 32; ++i) {
        float4 v = xp[i * 256 + tid];
        acc += __powf(v.x, g) + __powf(v.y, g) + __powf(v.z, g) + __powf(v.w, g);
    }

    // wave (64-lane) reduction
    #pragma unroll
    for (int off = 32; off > 0; off >>= 1)
        acc += __shfl_down(acc, off, 64);

    __shared__ float wsum[4];
    const int wave = tid >> 6;
    const int lane = tid & 63;
    if (lane == 0) wsum[wave] = acc;
    __syncthreads();
    if (tid == 0) {
        float s = (wsum[0] + wsum[1] + wsum[2] + wsum[3]) * wbc;
        atomicAdd(&sums[plane], s);
    }
}

// ---------------- Kernel 2: fused pointwise + 3x3 sharpen + blend ----------------
// grid = (32 row-tiles, 96 planes), 256 threads. Tile = 16 output rows x 512 cols.
// LDS holds 18 rows x (1 + 512 + 1) transformed values, stride 516 (16B-aligned rows).
#define TR 16
#define LSTRIDE 516

__global__ __launch_bounds__(256) void fuse_kernel(
    const float* __restrict__ x,
    const float* __restrict__ gamma,
    const float* __restrict__ wb,
    const float* __restrict__ contrast,
    const float* __restrict__ sharpen,
    const float* __restrict__ sums,
    float* __restrict__ out)
{
    __shared__ float tile[(TR + 2) * LSTRIDE];

    const int plane = blockIdx.y;              // 0..95
    const int tileY = blockIdx.x;              // 0..31
    const int b     = plane / 3;
    const float g    = gamma[b];
    const float wbc  = wb[plane];
    const float ct   = contrast[b];
    const float s    = sharpen[b];
    const float mean = sums[plane] * (1.0f / (float)NPLANE);

    const float* xp = x + (size_t)plane * NPLANE;
    const int y0  = tileY * TR;
    const int tid = threadIdx.x;

    // Stage 18 rows x 512 cols, transformed, into LDS (cols shifted +1 for halo).
    // 18*128 = 2304 float4 loads, 9 per thread.
    #pragma unroll
    for (int ii = 0; ii < 9; ++ii) {
        int i   = ii * 256 + tid;              // 0..2303
        int r   = i >> 7;                      // LDS row 0..17
        int c4  = i & 127;                     // float4 column
        int gy  = y0 - 1 + r;
        float* dst = &tile[r * LSTRIDE + 1 + c4 * 4];
        if (gy < 0 || gy >= HH) {
            dst[0] = 0.f; dst[1] = 0.f; dst[2] = 0.f; dst[3] = 0.f;
        } else {
            float4 v = ((const float4*)(xp + (size_t)gy * WW))[c4];
            dst[0] = tfm(v.x, g, wbc, mean, ct);
            dst[1] = tfm(v.y, g, wbc, mean, ct);
            dst[2] = tfm(v.z, g, wbc, mean, ct);
            dst[3] = tfm(v.w, g, wbc, mean, ct);
        }
    }
    // left/right zero padding columns
    if (tid < TR + 2) {
        tile[tid * LSTRIDE + 0]   = 0.f;
        tile[tid * LSTRIDE + 513] = 0.f;
    }
    __syncthreads();

    float* op = out + (size_t)plane * NPLANE;
    const float c1 = 1.0f + 9.0f * s;          // out = clip(c1*center - s*sum9)

    // 2048 output float4s, 8 per thread; consecutive tids -> consecutive float4s.
    #pragma unroll
    for (int ii = 0; ii < 8; ++ii) {
        int idx4 = ii * 256 + tid;             // 0..2047
        int oy   = idx4 >> 7;                  // 0..15
        int col  = (idx4 & 127) * 4;           // output col base (multiple of 4)

        const float* r0 = &tile[(oy    ) * LSTRIDE + col];
        const float* r1 = &tile[(oy + 1) * LSTRIDE + col];
        const float* r2 = &tile[(oy + 2) * LSTRIDE + col];

        // 6 column sums across the 3 rows
        float cs0 = r0[0] + r1[0] + r2[0];
        float cs1 = r0[1] + r1[1] + r2[1];
        float cs2 = r0[2] + r1[2] + r2[2];
        float cs3 = r0[3] + r1[3] + r2[3];
        float cs4 = r0[4] + r1[4] + r2[4];
        float cs5 = r0[5] + r1[5] + r2[5];

        float4 o;
        o.x = __saturatef(c1 * r1[1] - s * (cs0 + cs1 + cs2));
        o.y = __saturatef(c1 * r1[2] - s * (cs1 + cs2 + cs3));
        o.z = __saturatef(c1 * r1[3] - s * (cs2 + cs3 + cs4));
        o.w = __saturatef(c1 * r1[4] - s * (cs3 + cs4 + cs5));

        ((float4*)(op + (size_t)(y0 + oy) * WW + col))[0] = o;
    }
}

extern "C" void kernel_launch(void* const* d_in, const int* in_sizes, int n_in,
                              void* d_out, int out_size, void* d_ws, size_t ws_size,
                              hipStream_t stream) {
    const float* x        = (const float*)d_in[0];
    const float* gamma    = (const float*)d_in[1];
    const float* wb       = (const float*)d_in[2];
    const float* contrast = (const float*)d_in[3];
    const float* sharpen  = (const float*)d_in[4];
    float* out  = (float*)d_out;
    float* sums = (float*)d_ws;                // 96 floats of scratch

    hipMemsetAsync(sums, 0, NPLANES * sizeof(float), stream);
    mean_kernel<<<dim3(NPLANES * CHUNKS), 256, 0, stream>>>(x, gamma, wb, sums);
    fuse_kernel<<<dim3(32, NPLANES), 256, 0, stream>>>(x, gamma, wb, contrast,
                                                       sharpen, sums, out);
}

// Round 2
// 209.911 us; speedup vs baseline: 1.7991x; 1.7991x over previous
//
#include <hip/hip_runtime.h>

// B=32, C=3, H=W=512 fp32.
// x^gamma -> *wb -> contrast about per-plane mean (clip) -> 3x3 sharpen -> blend -> clip.
// K1: per-plane sums of x^g * wb (96 floats in d_ws).  K2: everything else, LDS tile.
//
// R1 lessons: HIP __powf == __ocml_pow_f32 (~100 instr) -> VALU-bound at 450 ops/elem.
//             +1-shifted LDS layout -> 8-way bank conflicts on every access.

#define HH 512
#define WW 512
#define NPLANE (HH * WW)
#define NPLANES 96
#define CHUNKS 8

// native pow: v_exp_f32(g * v_log_f32(x)). x in [0,1): log2(0)=-inf -> exp2 -> 0. exact.
__device__ __forceinline__ float fpow(float v, float g) {
    return __builtin_amdgcn_exp2f(g * __builtin_amdgcn_logf(v));
}

__device__ __forceinline__ float tfm(float v, float g, float wbc, float mean, float ct) {
    float p = fpow(v, g) * wbc;
    float t = (p - mean) * ct + mean;
    return __saturatef(t);
}

// ---------------- Kernel 1: per-plane sums of x^g * wb ----------------
__global__ __launch_bounds__(256) void mean_kernel(
    const float* __restrict__ x,
    const float* __restrict__ gamma,
    const float* __restrict__ wb,
    float* __restrict__ sums)
{
    const int blk   = blockIdx.x;
    const int plane = blk / CHUNKS;
    const int chunk = blk % CHUNKS;
    const int b     = plane / 3;
    const float g   = gamma[b];
    const float wbc = wb[plane];

    const float4* xp = (const float4*)(x + (size_t)plane * NPLANE)
                       + (size_t)chunk * (NPLANE / CHUNKS / 4);
    const int tid = threadIdx.x;

    float acc = 0.f;
    #pragma unroll
    for (int i = 0; i < 32; ++i) {
        float4 v = xp[i * 256 + tid];
        acc += fpow(v.x, g) + fpow(v.y, g) + fpow(v.z, g) + fpow(v.w, g);
    }

    #pragma unroll
    for (int off = 32; off > 0; off >>= 1)
        acc += __shfl_down(acc, off, 64);

    __shared__ float wsum[4];
    const int wave = tid >> 6;
    const int lane = tid & 63;
    if (lane == 0) wsum[wave] = acc;
    __syncthreads();
    if (tid == 0) {
        float s = (wsum[0] + wsum[1] + wsum[2] + wsum[3]) * wbc;
        atomicAdd(&sums[plane], s);
    }
}

// ---------------- Kernel 2: fused pointwise + 3x3 sharpen + blend ----------------
// Tile: 16 output rows x 512 cols per block. LDS: 18 rows, stride 520 floats,
// data at [r*520 + 4 + c] (4-float front pad -> aligned b128 staging writes,
// conflict-free). Conv phase: each thread owns 1 column x 4 vertical outputs;
// lanes cover 64 consecutive columns -> consecutive banks (2/bank = free).
#define TR 16
#define LSTRIDE 520

__global__ __launch_bounds__(256) void fuse_kernel(
    const float* __restrict__ x,
    const float* __restrict__ gamma,
    const float* __restrict__ wb,
    const float* __restrict__ contrast,
    const float* __restrict__ sharpen,
    const float* __restrict__ sums,
    float* __restrict__ out)
{
    __shared__ float tile[(TR + 2) * LSTRIDE];

    const int plane = blockIdx.y;
    const int tileY = blockIdx.x;
    const int b     = plane / 3;
    const float g    = gamma[b];
    const float wbc  = wb[plane];
    const float ct   = contrast[b];
    const float s    = sharpen[b];
    const float mean = sums[plane] * (1.0f / (float)NPLANE);

    const float* xp = x + (size_t)plane * NPLANE;
    const int y0  = tileY * TR;
    const int tid = threadIdx.x;

    // Stage 18 rows x 512 cols transformed into LDS. 2304 float4s, 9/thread.
    #pragma unroll
    for (int ii = 0; ii < 9; ++ii) {
        int i  = ii * 256 + tid;               // 0..2303
        int r  = i >> 7;                       // LDS row 0..17
        int c4 = i & 127;                      // float4 column
        int gy = y0 - 1 + r;
        float4* dst = (float4*)&tile[r * LSTRIDE + 4 + c4 * 4];
        if (gy < 0 || gy >= HH) {
            *dst = make_float4(0.f, 0.f, 0.f, 0.f);
        } else {
            float4 v = ((const float4*)(xp + (size_t)gy * WW))[c4];
            *dst = make_float4(tfm(v.x, g, wbc, mean, ct),
                               tfm(v.y, g, wbc, mean, ct),
                               tfm(v.z, g, wbc, mean, ct),
                               tfm(v.w, g, wbc, mean, ct));
        }
    }
    if (tid < TR + 2) {
        tile[tid * LSTRIDE + 3]   = 0.f;       // col -1
        tile[tid * LSTRIDE + 516] = 0.f;       // col 512
    }
    __syncthreads();

    float* op = out + (size_t)plane * NPLANE;
    const float c1 = 1.0f + 9.0f * s;          // out = clip(c1*center - s*sum9)

    const int lane = tid & 63;
    const int wave = tid >> 6;

    // 32 wave-tiles of (4 rows x 64 cols); 4 waves x 8 iters.
    #pragma unroll
    for (int ii = 0; ii < 8; ++ii) {
        int t   = ii * 4 + wave;               // 0..31
        int rg  = t & 3;
        int cg  = t >> 2;
        int c   = cg * 64 + lane;              // 0..511
        int oy0 = rg * 4;                      // tile-local output row base

        // LDS rows oy0..oy0+5 cover global rows y0+oy0-1 .. y0+oy0+4
        float h[6], mid[4];
        #pragma unroll
        for (int j = 0; j < 6; ++j) {
            const float* rp = &tile[(oy0 + j) * LSTRIDE + 4 + c];
            float a = rp[-1], m = rp[0], d = rp[1];
            h[j] = a + m + d;
            if (j >= 1 && j <= 4) mid[j - 1] = m;
        }
        #pragma unroll
        for (int j = 0; j < 4; ++j) {
            float o = __saturatef(c1 * mid[j] - s * (h[j] + h[j + 1] + h[j + 2]));
            op[(size_t)(y0 + oy0 + j) * WW + c] = o;
        }
    }
}

extern "C" void kernel_launch(void* const* d_in, const int* in_sizes, int n_in,
                              void* d_out, int out_size, void* d_ws, size_t ws_size,
                              hipStream_t stream) {
    const float* x        = (const float*)d_in[0];
    const float* gamma    = (const float*)d_in[1];
    const float* wb       = (const float*)d_in[2];
    const float* contrast = (const float*)d_in[3];
    const float* sharpen  = (const float*)d_in[4];
    float* out  = (float*)d_out;
    float* sums = (float*)d_ws;

    hipMemsetAsync(sums, 0, NPLANES * sizeof(float), stream);
    mean_kernel<<<dim3(NPLANES * CHUNKS), 256, 0, stream>>>(x, gamma, wb, sums);
    fuse_kernel<<<dim3(32, NPLANES), 256, 0, stream>>>(x, gamma, wb, contrast,
                                                       sharpen, sums, out);
}

// Round 3
// 199.174 us; speedup vs baseline: 1.8961x; 1.0539x over previous
//
#include <hip/hip_runtime.h>

// B=32, C=3, H=W=512 fp32.
// x^gamma -> *wb -> contrast about per-plane mean (clip) -> 3x3 sharpen -> blend -> clip.
// K1: per-plane-chunk partial sums of x^g (768 floats in d_ws, no memset/atomics).
// K2: fused pointwise + conv, LDS tile, b128 conv reads, NT b128 stores.
//
// R1: __powf == __ocml_pow_f32 -> VALU-bound. Use v_exp_f32/v_log_f32.
// R2: conv phase did 18 ds_read_b32 per 4 outputs -> ~17us LDS issue. Now 3
//     aligned ds_read_b128 per LDS row per lane (4 cols x 8 rows per lane).

#define HH 512
#define WW 512
#define NPLANE (HH * WW)
#define NPLANES 96
#define CHUNKS 8

typedef float f4 __attribute__((ext_vector_type(4)));

__device__ __forceinline__ float fpow(float v, float g) {
    return __builtin_amdgcn_exp2f(g * __builtin_amdgcn_logf(v));   // 0^g -> 0 exact
}
__device__ __forceinline__ float tfm(float v, float g, float wbc, float mean, float ct) {
    float p = fpow(v, g) * wbc;
    return __saturatef((p - mean) * ct + mean);
}

// ---------------- Kernel 1: per-(plane,chunk) partial sums of x^g ----------------
// grid = 96*8 blocks; block (plane,chunk) writes partials[plane*8+chunk].
// Every ws slot written every call (ws is re-poisoned 0xAA by the harness).
__global__ __launch_bounds__(256) void mean_kernel(
    const float* __restrict__ x,
    const float* __restrict__ gamma,
    float* __restrict__ partials)
{
    const int blk   = blockIdx.x;
    const int plane = blk / CHUNKS;
    const float g   = gamma[plane / 3];

    const float4* xp = (const float4*)(x + (size_t)plane * NPLANE)
                       + (size_t)(blk % CHUNKS) * (NPLANE / CHUNKS / 4);
    const int tid = threadIdx.x;

    float acc = 0.f;
    #pragma unroll
    for (int i = 0; i < 32; ++i) {
        float4 v = xp[i * 256 + tid];
        acc += fpow(v.x, g) + fpow(v.y, g) + fpow(v.z, g) + fpow(v.w, g);
    }
    #pragma unroll
    for (int off = 32; off > 0; off >>= 1)
        acc += __shfl_down(acc, off, 64);

    __shared__ float wsum[4];
    if ((tid & 63) == 0) wsum[tid >> 6] = acc;
    __syncthreads();
    if (tid == 0) partials[blk] = wsum[0] + wsum[1] + wsum[2] + wsum[3];
}

// ---------------- Kernel 2: fused pointwise + 3x3 sharpen + blend ----------------
// Tile 16 rows x 512 cols. LDS rows stride 520 floats; data col c at idx 4+c,
// left pad idx 3, right pad idx 516 -> aligned b128 staging writes AND aligned
// b128 conv reads (A=[c0-4..c0-1], B=[c0..c0+3], C=[c0+4..c0+7]); only A.w /
// B.* / C.x are used arithmetically, so unwritten idx 0..2 / 517..519 are inert.
#define TR 16
#define LSTRIDE 520

__global__ __launch_bounds__(256, 4) void fuse_kernel(
    const float* __restrict__ x,
    const float* __restrict__ gamma,
    const float* __restrict__ wb,
    const float* __restrict__ contrast,
    const float* __restrict__ sharpen,
    const float* __restrict__ partials,
    float* __restrict__ out)
{
    __shared__ float tile[(TR + 2) * LSTRIDE];

    const int plane = blockIdx.y;
    const int tileY = blockIdx.x;
    const int b     = plane / 3;
    const float g   = gamma[b];
    const float wbc = wb[plane];
    const float ct  = contrast[b];
    const float s   = sharpen[b];

    float psum = 0.f;
    const float* pp = partials + plane * CHUNKS;
    #pragma unroll
    for (int i = 0; i < CHUNKS; ++i) psum += pp[i];
    const float mean = psum * wbc * (1.0f / (float)NPLANE);

    const float* xp = x + (size_t)plane * NPLANE;
    const int y0  = tileY * TR;
    const int tid = threadIdx.x;

    // Stage 18 rows x 512 cols transformed into LDS. 2304 float4s, 9/thread.
    #pragma unroll
    for (int ii = 0; ii < 9; ++ii) {
        int i  = ii * 256 + tid;
        int r  = i >> 7;
        int c4 = i & 127;
        int gy = y0 - 1 + r;
        float4* dst = (float4*)&tile[r * LSTRIDE + 4 + c4 * 4];
        if (gy < 0 || gy >= HH) {
            *dst = make_float4(0.f, 0.f, 0.f, 0.f);
        } else {
            float4 v = ((const float4*)(xp + (size_t)gy * WW))[c4];
            *dst = make_float4(tfm(v.x, g, wbc, mean, ct),
                               tfm(v.y, g, wbc, mean, ct),
                               tfm(v.z, g, wbc, mean, ct),
                               tfm(v.w, g, wbc, mean, ct));
        }
    }
    if (tid < TR + 2) {
        tile[tid * LSTRIDE + 3]   = 0.f;   // col -1
        tile[tid * LSTRIDE + 516] = 0.f;   // col 512
    }
    __syncthreads();

    float* op = out + (size_t)plane * NPLANE;
    const float c1 = 1.0f + 9.0f * s;      // out = clip(c1*center - s*sum9)

    const int lane = tid & 63;
    const int wave = tid >> 6;
    const int cg   = wave & 1;             // column half: 0..1
    const int rg   = wave >> 1;            // row half: 0..1
    const int c0   = cg * 256 + lane * 4;  // this lane's 4 output cols
    const int jb   = rg * 8;               // tile-local output row base

    // load LDS row r: h = 3-col sums for the 4 cols, m = center values
    auto ldrow = [&](int r, f4& h, f4& m) {
        const float* p = &tile[r * LSTRIDE + c0];
        f4 A = *(const f4*)(p);            // cols c0-4 .. c0-1 (use .w)
        f4 B = *(const f4*)(p + 4);        // cols c0   .. c0+3
        f4 C = *(const f4*)(p + 8);        // cols c0+4 .. c0+7 (use .x)
        h.x = A.w + B.x + B.y;
        h.y = B.x + B.y + B.z;
        h.z = B.y + B.z + B.w;
        h.w = B.z + B.w + C.x;
        m = B;
    };

    f4 h0, h1, h2, m1, m2, mdum;
    ldrow(jb,     h0, mdum);
    ldrow(jb + 1, h1, m1);

    #pragma unroll 4
    for (int j = 0; j < 8; ++j) {
        ldrow(jb + 2 + j, h2, m2);
        f4 sum = h0 + h1 + h2;
        f4 o;
        o.x = __saturatef(fmaf(c1, m1.x, -s * sum.x));
        o.y = __saturatef(fmaf(c1, m1.y, -s * sum.y));
        o.z = __saturatef(fmaf(c1, m1.z, -s * sum.z));
        o.w = __saturatef(fmaf(c1, m1.w, -s * sum.w));
        __builtin_nontemporal_store(o, (f4*)(op + (size_t)(y0 + jb + j) * WW + c0));
        h0 = h1; h1 = h2; m1 = m2;
    }
}

extern "C" void kernel_launch(void* const* d_in, const int* in_sizes, int n_in,
                              void* d_out, int out_size, void* d_ws, size_t ws_size,
                              hipStream_t stream) {
    const float* x        = (const float*)d_in[0];
    const float* gamma    = (const float*)d_in[1];
    const float* wb       = (const float*)d_in[2];
    const float* contrast = (const float*)d_in[3];
    const float* sharpen  = (const float*)d_in[4];
    float* out      = (float*)d_out;
    float* partials = (float*)d_ws;        // 768 floats, fully rewritten each call

    mean_kernel<<<dim3(NPLANES * CHUNKS), 256, 0, stream>>>(x, gamma, partials);
    fuse_kernel<<<dim3(32, NPLANES), 256, 0, stream>>>(x, gamma, wb, contrast,
                                                       sharpen, partials, out);
}